// Round 24
// baseline (249.345 us; speedup 1.0000x reference)
//
#include <hip/hip_runtime.h>

#define B_ 512
#define T_ 512
#define V_ 96
#define H_ 128
#define NKS 7     // K-slices: 4 for h (K=128) + 3 for one-hot (K=96)
#define OXP 104   // one-hot row stride (halfs): 208B, same 8-class spread as hs
#define K2F 2.8853900817779268f   // 2*log2(e): exp(2s) == exp2(K2F*s)

typedef _Float16 half8 __attribute__((ext_vector_type(8)));
typedef float    f32x4 __attribute__((ext_vector_type(4)));

// Pass 1a: recover the one-hot index per (b,t). x is exactly {0.0, 1.0}.
__global__ __launch_bounds__(256) void onehot_idx_kernel(
    const float4* __restrict__ x4, int n4, int* __restrict__ idx)
{
    int stride = gridDim.x * blockDim.x;
    for (int e4 = blockIdx.x * blockDim.x + threadIdx.x; e4 < n4; e4 += stride) {
        float4 v = x4[e4];
        int base = e4 * 4;
        if (v.x > 0.5f) idx[(base + 0) / V_] = (base + 0) % V_;
        if (v.y > 0.5f) idx[(base + 1) / V_] = (base + 1) % V_;
        if (v.z > 0.5f) idx[(base + 2) / V_] = (base + 2) % V_;
        if (v.w > 0.5f) idx[(base + 3) / V_] = (base + 3) % V_;
    }
}

// Pass 1c (extends the R16/R21-VERIFIED builder to K=224): weight A-frags.
// frag (ks,mt): lane holds A[m=mt*16+(lane&15)][k=ks*32+(lane>>4)*8+reg].
// k < 128: K2F*W_hh[m][k].  k >= 128 (one-hot column v=k-128):
// K2F*(W_ih[m][v] + b_ih[m] + b_hh[m]) -- biases fold because exactly one
// one-hot element is 1. The xw gather disappears into the MFMA.
__global__ __launch_bounds__(256) void build_wB_kernel(
    const float* __restrict__ W_hh, const float* __restrict__ W_ih,
    const float* __restrict__ b_ih, const float* __restrict__ b_hh,
    _Float16* __restrict__ wB)
{
    int e = blockIdx.x * 256 + threadIdx.x;     // 7ks*8mt*64lane*8reg = 28672
    if (e < NKS * 8 * 64 * 8) {
        int reg = e & 7, lane = (e >> 3) & 63, mt = (e >> 9) & 7, ks = e >> 12;
        int k = ks * 32 + ((lane >> 4) << 3) + reg;
        int m = mt * 16 + (lane & 15);
        float val;
        if (k < H_) val = K2F * W_hh[m * H_ + k];
        else {
            int v = k - H_;
            val = K2F * (W_ih[m * V_ + v] + b_ih[m] + b_hh[m]);
        }
        wB[e] = (_Float16)val;
    }
}

// Pass 1d (R16/R21-VERIFIED): fc A-frags (unscaled W_fc), 6 m-tiles, K=128.
__global__ __launch_bounds__(256) void build_wBfc_kernel(
    const float* __restrict__ W_fc, _Float16* __restrict__ wBfc)
{
    int e = blockIdx.x * 256 + threadIdx.x;     // 4*6*64*8 = 12288
    if (e < 12288) {
        int reg = e & 7, lane = (e >> 3) & 63;
        int mt = (e >> 9) % 6, ks = e / 3072;
        int kin = ks * 32 + ((lane >> 4) << 3) + reg;
        int m   = mt * 16 + (lane & 15);
        wBfc[e] = (_Float16)W_fc[m * H_ + kin];
    }
}

// Pass 2: R21 structure (4 waves / 16 rows / block, grid=32, swapped MFMA,
// zero vmem in loop) with the xw gather FOLDED INTO THE MFMA (K=224).
// Per step: 7x ds_read_b128 (4 h + 3 one-hot) + 14 MFMA + tail + 2x b64
// write + one-hot maintenance (16 lanes, 2x b16) + __syncthreads.
// The 8-class gather pileup (~1M conflicts, un-fixable by addressing) and
// the C-init dependency are gone.
__global__ __launch_bounds__(256, 1) void rnn_mfma4_kernel(
    const uint4* __restrict__ wBg, const uint4* __restrict__ wBfcg,
    const int* __restrict__ idx, const float* __restrict__ b_fc,
    float* __restrict__ out)
{
    const int bb  = blockIdx.x;        // rows 16*bb .. 16*bb+15
    const int tid = threadIdx.x;
    const int w   = tid >> 6;          // wave 0..3 -> unit m-tiles {2w, 2w+1}
    const int l   = tid & 63;
    const int lo  = l & 15, g = l >> 4;

    __shared__ _Float16      hs[2][16][136];      // dbl-buffered h[row][unit]
    __shared__ _Float16      ox[2][16][OXP];      // dbl-buffered one-hot ext
    __shared__ unsigned char idxT[(T_ + 1) * 16]; // [t][row] char ids

    for (int e = tid; e < 16 * T_; e += 256) {
        int row = e >> 9, t = e & 511;
        idxT[t * 16 + row] = (unsigned char)idx[(bb * 16 + row) * T_ + t];
    }
    if (tid < 16) idxT[T_ * 16 + tid] = 0;        // pad for t+1 lookahead
    for (int e = tid; e < 16 * 136; e += 256)
        hs[0][e / 136][e % 136] = (_Float16)0.f;
    for (int e = tid; e < 2 * 16 * OXP; e += 256) {
        int buf = e / (16 * OXP), rem = e % (16 * OXP);
        ox[buf][rem / OXP][rem % OXP] = (_Float16)0.f;
    }

    // this wave's weight A-frags: 14 x uint4 = 56 regs, loaded ONCE
    uint4 wa[NKS][2];
    #pragma unroll
    for (int ks = 0; ks < NKS; ++ks)
        #pragma unroll
        for (int q = 0; q < 2; ++q)
            wa[ks][q] = wBg[(ks * 8 + 2 * w + q) * 64 + l];

    __syncthreads();                   // zeroing complete before one-hot set

    int idA = 0, idB = 0;              // ids currently set in ox[0] / ox[1]
    if (tid < 16) {
        idA = idxT[0 * 16 + tid];
        idB = idxT[1 * 16 + tid];
        ox[0][tid][idA] = (_Float16)1.f;
        ox[1][tid][idB] = (_Float16)1.f;
    }
    __syncthreads();

    int cur = 0;
    #pragma clang loop unroll(disable)
    for (int t = 0; t < T_; ++t) {
        // B-frags: extended state h' of own row (7x b128, k-contiguous)
        half8 bF[NKS];
        #pragma unroll
        for (int ks = 0; ks < 4; ++ks)
            __builtin_memcpy(&bF[ks], &hs[cur][lo][ks * 32 + g * 8], 16);
        #pragma unroll
        for (int ks = 4; ks < NKS; ++ks)
            __builtin_memcpy(&bF[ks], &ox[cur][lo][(ks - 4) * 32 + g * 8], 16);

        // 14 MFMAs: 2+2+3 split chains per m-tile, C-init = 0
        f32x4 p0 = {0.f,0.f,0.f,0.f}, p1 = {0.f,0.f,0.f,0.f};
        f32x4 q0 = {0.f,0.f,0.f,0.f}, q1 = {0.f,0.f,0.f,0.f};
        f32x4 r0 = {0.f,0.f,0.f,0.f}, r1 = {0.f,0.f,0.f,0.f};
        #pragma unroll
        for (int ks = 0; ks < 2; ++ks) {
            union { uint4 u; half8 h; } u0, u1, u2, u3;
            u0.u = wa[ks][0];     u1.u = wa[ks][1];
            u2.u = wa[ks + 2][0]; u3.u = wa[ks + 2][1];
            p0 = __builtin_amdgcn_mfma_f32_16x16x32_f16(u0.h, bF[ks],     p0, 0, 0, 0);
            p1 = __builtin_amdgcn_mfma_f32_16x16x32_f16(u1.h, bF[ks],     p1, 0, 0, 0);
            q0 = __builtin_amdgcn_mfma_f32_16x16x32_f16(u2.h, bF[ks + 2], q0, 0, 0, 0);
            q1 = __builtin_amdgcn_mfma_f32_16x16x32_f16(u3.h, bF[ks + 2], q1, 0, 0, 0);
        }
        #pragma unroll
        for (int ks = 4; ks < NKS; ++ks) {
            union { uint4 u; half8 h; } u0, u1;
            u0.u = wa[ks][0]; u1.u = wa[ks][1];
            r0 = __builtin_amdgcn_mfma_f32_16x16x32_f16(u0.h, bF[ks], r0, 0, 0, 0);
            r1 = __builtin_amdgcn_mfma_f32_16x16x32_f16(u1.h, bF[ks], r1, 0, 0, 0);
        }
        f32x4 acc0 = (p0 + q0) + r0, acc1 = (p1 + q1) + r1;

        // tail: tanh(s) = 1 - 2/(exp2(acc)+1); pack 4 halves -> one b64 write
        _Float16 o0[4], o1[4];
        #pragma unroll
        for (int j = 0; j < 4; ++j) {
            float E0 = __builtin_amdgcn_exp2f(acc0[j]);
            float E1 = __builtin_amdgcn_exp2f(acc1[j]);
            o0[j] = (_Float16)(1.0f - 2.0f * __builtin_amdgcn_rcpf(E0 + 1.0f));
            o1[j] = (_Float16)(1.0f - 2.0f * __builtin_amdgcn_rcpf(E1 + 1.0f));
        }
        __builtin_memcpy(&hs[cur ^ 1][lo][32 * w + 4 * g], o0, 8);
        __builtin_memcpy(&hs[cur ^ 1][lo][32 * w + 16 + 4 * g], o1, 8);

        // one-hot maintenance for step t+1 in buffer cur^1 (16 lanes):
        // clear the id set two steps ago, set id_{t+1}.
        if (tid < 16) {
            const int oldid = cur ? idA : idB;
            const int idn   = idxT[(t + 1) * 16 + tid];
            ox[cur ^ 1][tid][oldid] = (_Float16)0.f;
            ox[cur ^ 1][tid][idn]   = (_Float16)1.f;
            if (cur) idA = idn; else idB = idn;
        }
        cur ^= 1;
        __syncthreads();                       // lgkm-only drain (no vmem)
    }

    // fc epilogue: D[m=vocab][n=row]; wave w does vocab m-tiles {2w,2w+1}<6
    half8 bE[4];
    #pragma unroll
    for (int ks = 0; ks < 4; ++ks)
        __builtin_memcpy(&bE[ks], &hs[0][lo][ks * 32 + g * 8], 16);
    #pragma unroll
    for (int q = 0; q < 2; ++q) {
        const int MT = 2 * w + q;
        if (MT < 6) {
            f32x4 acc;
            __builtin_memcpy(&acc, &b_fc[MT * 16 + 4 * g], 16);  // C-init bias
            #pragma unroll
            for (int ks = 0; ks < 4; ++ks) {
                union { uint4 u; half8 h; } ua;
                ua.u = wBfcg[(ks * 6 + MT) * 64 + l];
                acc = __builtin_amdgcn_mfma_f32_16x16x32_f16(ua.h, bE[ks], acc, 0, 0, 0);
            }
            __builtin_memcpy(&out[(bb * 16 + lo) * V_ + MT * 16 + 4 * g], &acc, 16);
        }
    }
}

extern "C" void kernel_launch(void* const* d_in, const int* in_sizes, int n_in,
                              void* d_out, int out_size, void* d_ws, size_t ws_size,
                              hipStream_t stream)
{
    const float* x    = (const float*)d_in[0];
    const float* W_ih = (const float*)d_in[1];
    const float* b_ih = (const float*)d_in[2];
    const float* W_hh = (const float*)d_in[3];
    const float* b_hh = (const float*)d_in[4];
    const float* W_fc = (const float*)d_in[5];
    const float* b_fc = (const float*)d_in[6];
    float* out = (float*)d_out;

    char* ws = (char*)d_ws;
    int*      idx  = (int*)ws;                               // 1 MiB
    _Float16* wB   = (_Float16*)(ws + (size_t)B_ * T_ * 4);  // 56 KiB
    _Float16* wBfc = (_Float16*)((char*)wB + NKS * 8 * 64 * 8 * 2); // 24 KiB

    const int n4 = (B_ * T_ * V_) / 4;
    hipLaunchKernelGGL(onehot_idx_kernel, dim3(2048), dim3(256), 0, stream,
                       (const float4*)x, n4, idx);
    hipLaunchKernelGGL(build_wB_kernel, dim3((NKS * 8 * 64 * 8 + 255) / 256),
                       dim3(256), 0, stream, W_hh, W_ih, b_ih, b_hh, wB);
    hipLaunchKernelGGL(build_wBfc_kernel, dim3(48), dim3(256), 0, stream, W_fc, wBfc);
    hipLaunchKernelGGL(rnn_mfma4_kernel, dim3(B_ / 16), dim3(256), 0, stream,
                       (const uint4*)wB, (const uint4*)wBfc, idx, b_fc, out);
}

// Round 25
// 215.082 us; speedup vs baseline: 1.1593x; 1.1593x over previous
//
#include <hip/hip_runtime.h>

#define B_ 512
#define T_ 512
#define V_ 96
#define H_ 128
#define XST 132   // xwl row stride (floats)
#define K2F 2.8853900817779268f   // 2*log2(e): exp(2s) == exp2(K2F*s)

typedef _Float16 half8 __attribute__((ext_vector_type(8)));
typedef float    f32x4 __attribute__((ext_vector_type(4)));

// Pass 1a: recover the one-hot index per (b,t). x is exactly {0.0, 1.0}.
__global__ __launch_bounds__(256) void onehot_idx_kernel(
    const float4* __restrict__ x4, int n4, int* __restrict__ idx)
{
    int stride = gridDim.x * blockDim.x;
    for (int e4 = blockIdx.x * blockDim.x + threadIdx.x; e4 < n4; e4 += stride) {
        float4 v = x4[e4];
        int base = e4 * 4;
        if (v.x > 0.5f) idx[(base + 0) / V_] = (base + 0) % V_;
        if (v.y > 0.5f) idx[(base + 1) / V_] = (base + 1) % V_;
        if (v.z > 0.5f) idx[(base + 2) / V_] = (base + 2) % V_;
        if (v.w > 0.5f) idx[(base + 3) / V_] = (base + 3) % V_;
    }
}

// Pass 1b: PLAIN xwg[v][u] = (W_ih[u][v] + b_ih[u] + b_hh[u]) * K2F.
__global__ __launch_bounds__(256) void build_xwg_kernel(
    const float* __restrict__ W_ih, const float* __restrict__ b_ih,
    const float* __restrict__ b_hh, float* __restrict__ xwg)
{
    int e = blockIdx.x * 256 + threadIdx.x;
    if (e < V_ * H_) {
        int v = e >> 7, u = e & 127;
        xwg[e] = (W_ih[u * V_ + v] + b_ih[u] + b_hh[u]) * K2F;
    }
}

// Pass 1c (R16/R21-VERIFIED): weight A-frags, K2F pre-scaled f16.
// frag (ks,mt): lane holds A[m=mt*16+(lane&15)][k=ks*32+(lane>>4)*8+reg].
__global__ __launch_bounds__(256) void build_wB_kernel(
    const float* __restrict__ W_hh, _Float16* __restrict__ wB)
{
    int e = blockIdx.x * 256 + threadIdx.x;     // 4ks*8mt*64lane*8reg = 16384
    if (e < 16384) {
        int reg = e & 7, lane = (e >> 3) & 63, mt = (e >> 9) & 7, ks = e >> 12;
        int kin = ks * 32 + (lane >> 4) * 8 + reg;
        int m   = mt * 16 + (lane & 15);
        wB[e] = (_Float16)(K2F * W_hh[m * H_ + kin]);
    }
}

// Pass 1d (R16/R21-VERIFIED): fc A-frags (unscaled W_fc), 6 m-tiles.
__global__ __launch_bounds__(256) void build_wBfc_kernel(
    const float* __restrict__ W_fc, _Float16* __restrict__ wBfc)
{
    int e = blockIdx.x * 256 + threadIdx.x;     // 4*6*64*8 = 12288
    if (e < 12288) {
        int reg = e & 7, lane = (e >> 3) & 63;
        int mt = (e >> 9) % 6, ks = e / 3072;
        int kin = ks * 32 + (lane >> 4) * 8 + reg;
        int m   = mt * 16 + (lane & 15);
        wBfc[e] = (_Float16)W_fc[m * H_ + kin];
    }
}

// Pass 2 (R21, the verified best structure): 4 waves / 16 rows / block,
// grid=32, swapped MFMA (D[m=unit][n=row]), zero vmem in the loop, LDS xw
// gather, + id carried one step ahead in a register (the only piece of
// R22 that was never tested in isolation; moves the idx ds_read_u8 off
// the barrier-exit critical path).
__global__ __launch_bounds__(256, 1) void rnn_mfma4_kernel(
    const uint4* __restrict__ wBg, const uint4* __restrict__ wBfcg,
    const float* __restrict__ xwg, const int* __restrict__ idx,
    const float* __restrict__ b_fc, float* __restrict__ out)
{
    const int bb  = blockIdx.x;        // rows 16*bb .. 16*bb+15
    const int tid = threadIdx.x;
    const int w   = tid >> 6;          // wave 0..3 -> unit m-tiles {2w, 2w+1}
    const int l   = tid & 63;
    const int lo  = l & 15, g = l >> 4;

    __shared__ float         xwl[V_ * XST];   // 50.7 KiB gather table [v][u]
    __shared__ _Float16      hs[2][16][136];  // dbl-buffered h[row][unit]
    __shared__ unsigned char idxT[(T_ + 1) * 16];  // [t][row] char ids

    for (int e = tid; e < V_ * H_; e += 256) {
        int v = e >> 7, u = e & 127;
        xwl[v * XST + u] = xwg[e];
    }
    for (int e = tid; e < 16 * T_; e += 256) {
        int row = e >> 9, t = e & 511;
        idxT[t * 16 + row] = (unsigned char)idx[(bb * 16 + row) * T_ + t];
    }
    if (tid < 16) idxT[T_ * 16 + tid] = 0;    // pad for t+1 lookahead
    for (int e = tid; e < 16 * 136; e += 256)
        hs[0][e / 136][e % 136] = (_Float16)0.f;

    // this wave's weight A-frags: 8 x uint4 = 32 regs, loaded ONCE
    uint4 wa[4][2];
    #pragma unroll
    for (int ks = 0; ks < 4; ++ks)
        #pragma unroll
        for (int q = 0; q < 2; ++q)
            wa[ks][q] = wBg[(ks * 8 + 2 * w + q) * 64 + l];

    __syncthreads();

    int id = idxT[0 * 16 + lo];        // t=0 id ready before the loop
    int cur = 0;
    #pragma clang loop unroll(disable)
    for (int t = 0; t < T_; ++t) {
        const int idn = idxT[(t + 1) * 16 + lo];   // prefetch next step's id

        // xw C-init gather: units {32w+4g..+3} and {32w+16+4g..+3} of row id
        f32x4 xw0, xw1;
        __builtin_memcpy(&xw0, &xwl[id * XST + 32 * w + 4 * g], 16);
        __builtin_memcpy(&xw1, &xwl[id * XST + 32 * w + 16 + 4 * g], 16);

        // B-frags: h_{t-1} of own row, k-contiguous (4x b128)
        half8 bF[4];
        #pragma unroll
        for (int ks = 0; ks < 4; ++ks)
            __builtin_memcpy(&bF[ks], &hs[cur][lo][ks * 32 + g * 8], 16);

        // 8 MFMAs, 2+2 split chains; xw folded as C-init of the p-chains
        f32x4 p0 = xw0, p1 = xw1;
        f32x4 q0 = {0.f, 0.f, 0.f, 0.f}, q1 = {0.f, 0.f, 0.f, 0.f};
        #pragma unroll
        for (int ks = 0; ks < 2; ++ks) {
            union { uint4 u; half8 h; } u0, u1, u2, u3;
            u0.u = wa[ks][0];     u1.u = wa[ks][1];
            u2.u = wa[ks + 2][0]; u3.u = wa[ks + 2][1];
            p0 = __builtin_amdgcn_mfma_f32_16x16x32_f16(u0.h, bF[ks],     p0, 0, 0, 0);
            p1 = __builtin_amdgcn_mfma_f32_16x16x32_f16(u1.h, bF[ks],     p1, 0, 0, 0);
            q0 = __builtin_amdgcn_mfma_f32_16x16x32_f16(u2.h, bF[ks + 2], q0, 0, 0, 0);
            q1 = __builtin_amdgcn_mfma_f32_16x16x32_f16(u3.h, bF[ks + 2], q1, 0, 0, 0);
        }
        f32x4 acc0 = p0 + q0, acc1 = p1 + q1;

        // tail: tanh(s) = 1 - 2/(exp2(acc)+1); pack 4 halves -> one b64 write
        _Float16 o0[4], o1[4];
        #pragma unroll
        for (int j = 0; j < 4; ++j) {
            float E0 = __builtin_amdgcn_exp2f(acc0[j]);
            float E1 = __builtin_amdgcn_exp2f(acc1[j]);
            o0[j] = (_Float16)(1.0f - 2.0f * __builtin_amdgcn_rcpf(E0 + 1.0f));
            o1[j] = (_Float16)(1.0f - 2.0f * __builtin_amdgcn_rcpf(E1 + 1.0f));
        }
        __builtin_memcpy(&hs[cur ^ 1][lo][32 * w + 4 * g], o0, 8);
        __builtin_memcpy(&hs[cur ^ 1][lo][32 * w + 16 + 4 * g], o1, 8);
        id = idn;
        cur ^= 1;
        __syncthreads();                       // lgkm-only drain
    }

    // fc epilogue: D[m=vocab][n=row]; wave w does vocab m-tiles {2w,2w+1}<6
    half8 bE[4];
    #pragma unroll
    for (int ks = 0; ks < 4; ++ks)
        __builtin_memcpy(&bE[ks], &hs[0][lo][ks * 32 + g * 8], 16);
    #pragma unroll
    for (int q = 0; q < 2; ++q) {
        const int MT = 2 * w + q;
        if (MT < 6) {
            f32x4 acc;
            __builtin_memcpy(&acc, &b_fc[MT * 16 + 4 * g], 16);  // C-init bias
            #pragma unroll
            for (int ks = 0; ks < 4; ++ks) {
                union { uint4 u; half8 h; } ua;
                ua.u = wBfcg[(ks * 6 + MT) * 64 + l];
                acc = __builtin_amdgcn_mfma_f32_16x16x32_f16(ua.h, bE[ks], acc, 0, 0, 0);
            }
            __builtin_memcpy(&out[(bb * 16 + lo) * V_ + MT * 16 + 4 * g], &acc, 16);
        }
    }
}

extern "C" void kernel_launch(void* const* d_in, const int* in_sizes, int n_in,
                              void* d_out, int out_size, void* d_ws, size_t ws_size,
                              hipStream_t stream)
{
    const float* x    = (const float*)d_in[0];
    const float* W_ih = (const float*)d_in[1];
    const float* b_ih = (const float*)d_in[2];
    const float* W_hh = (const float*)d_in[3];
    const float* b_hh = (const float*)d_in[4];
    const float* W_fc = (const float*)d_in[5];
    const float* b_fc = (const float*)d_in[6];
    float* out = (float*)d_out;

    char* ws = (char*)d_ws;
    int*      idx  = (int*)ws;                               // 1 MiB
    float*    xwg  = (float*)(ws + (size_t)B_ * T_ * 4);     // 48 KiB
    _Float16* wB   = (_Float16*)((char*)xwg + V_ * H_ * 4);  // 32 KiB
    _Float16* wBfc = (_Float16*)((char*)wB + 16384 * 2);     // 24 KiB

    const int n4 = (B_ * T_ * V_) / 4;
    hipLaunchKernelGGL(onehot_idx_kernel, dim3(2048), dim3(256), 0, stream,
                       (const float4*)x, n4, idx);
    hipLaunchKernelGGL(build_xwg_kernel, dim3((V_ * H_ + 255) / 256), dim3(256),
                       0, stream, W_ih, b_ih, b_hh, xwg);
    hipLaunchKernelGGL(build_wB_kernel, dim3(64), dim3(256), 0, stream, W_hh, wB);
    hipLaunchKernelGGL(build_wBfc_kernel, dim3(48), dim3(256), 0, stream, W_fc, wBfc);
    hipLaunchKernelGGL(rnn_mfma4_kernel, dim3(B_ / 16), dim3(256), 0, stream,
                       (const uint4*)wB, (const uint4*)wBfc, xwg, idx, b_fc, out);
}